// Round 3
// baseline (747.822 us; speedup 1.0000x reference)
//
#include <hip/hip_runtime.h>
#include <stdint.h>

typedef float  f32x4  __attribute__((ext_vector_type(4)));
typedef __bf16 bf16x4 __attribute__((ext_vector_type(4)));
typedef __bf16 bf16x8 __attribute__((ext_vector_type(8)));
typedef short  short8 __attribute__((ext_vector_type(8)));

#define DD 4096      // state dimension
#define NB 256       // batch

static __device__ __forceinline__ f32x4 mfma16(bf16x8 a, bf16x8 b, f32x4 c) {
    return __builtin_amdgcn_mfma_f32_16x16x32_bf16(a, b, c, 0, 0, 0);
}

// ---------------------------------------------------------------- perm ----
// perm[j] = p_0(p_1(...p_{n-1}(j))) with p_i(v) = v ^ (((v>>c_i)&1)<<t_i),
// c_i = 11-i, t_i = (i==11) ? 11 : 10-i   (n_wires = 12)
__global__ void perm_kernel(int* __restrict__ perm) {
    int j = blockIdx.x * 256 + threadIdx.x;
    int v = j;
    #pragma unroll
    for (int i = 11; i >= 0; --i) {
        int c = 11 - i;
        int t = (i == 11) ? 11 : (10 - i);
        v ^= ((v >> c) & 1) << t;
    }
    perm[j] = v;
}

// ----------------------------------------------------------- normalize ----
__global__ __launch_bounds__(256) void normalize_kernel(
    const float* __restrict__ x, __bf16* __restrict__ sr)
{
    const int b = blockIdx.x;
    const int t = threadIdx.x;
    const float4* row = (const float4*)(x + (size_t)b * DD);
    float4 v0 = row[t], v1 = row[t + 256], v2 = row[t + 512], v3 = row[t + 768];
    float ss = v0.x*v0.x + v0.y*v0.y + v0.z*v0.z + v0.w*v0.w
             + v1.x*v1.x + v1.y*v1.y + v1.z*v1.z + v1.w*v1.w
             + v2.x*v2.x + v2.y*v2.y + v2.z*v2.z + v2.w*v2.w
             + v3.x*v3.x + v3.y*v3.y + v3.z*v3.z + v3.w*v3.w;
    #pragma unroll
    for (int off = 32; off; off >>= 1) ss += __shfl_down(ss, off);
    __shared__ float wsum[4];
    if ((t & 63) == 0) wsum[t >> 6] = ss;
    __syncthreads();
    float rs = rsqrtf(wsum[0] + wsum[1] + wsum[2] + wsum[3]);
    bf16x4* o = (bf16x4*)(sr + (size_t)b * DD);
    bf16x4 w;
    w.x = (__bf16)(v0.x * rs); w.y = (__bf16)(v0.y * rs);
    w.z = (__bf16)(v0.z * rs); w.w = (__bf16)(v0.w * rs); o[t] = w;
    w.x = (__bf16)(v1.x * rs); w.y = (__bf16)(v1.y * rs);
    w.z = (__bf16)(v1.z * rs); w.w = (__bf16)(v1.w * rs); o[t + 256] = w;
    w.x = (__bf16)(v2.x * rs); w.y = (__bf16)(v2.y * rs);
    w.z = (__bf16)(v2.z * rs); w.w = (__bf16)(v2.w * rs); o[t + 512] = w;
    w.x = (__bf16)(v3.x * rs); w.y = (__bf16)(v3.y * rs);
    w.z = (__bf16)(v3.z * rs); w.w = (__bf16)(v3.w * rs); o[t + 768] = w;
}

// -------------------------------------------------------------- gather ----
// out[b][j] = in[b][perm[j]]; reads hit an 8KB row (L1/L2-resident)
__global__ __launch_bounds__(256) void gather_kernel(
    const int* __restrict__ perm,
    const __bf16* __restrict__ inR, const __bf16* __restrict__ inI,
    __bf16* __restrict__ outR, __bf16* __restrict__ outI)
{
    const int b = blockIdx.x;
    const __bf16* ir = inR + (size_t)b * DD;
    const __bf16* ii = inI + (size_t)b * DD;
    __bf16* xr = outR + (size_t)b * DD;
    __bf16* xi = outI + (size_t)b * DD;
    #pragma unroll
    for (int q = 0; q < 16; ++q) {
        int j = threadIdx.x + q * 256;
        int p = perm[j];
        xr[j] = ir[p];
        xi[j] = ii[p];
    }
}

// ---------------------------------------------------------------- GEMM ----
// out[b][i] = sum_j U[i][j] * s[b][j]  (complex), M=256 N=4096 K=4096
// BM=BN=64, BK=32; 4 waves (2x2); each wave: 2x2 frags of 16x16x32 bf16 MFMA.
// acc_r += sr*Ur - si*Ui ; acc_i += sr*Ui + si*Ur
template<bool HAS_IMAG, bool FINAL>
__global__ __launch_bounds__(256, 1) void cgemm_kernel(
    const __bf16* __restrict__ Sr, const __bf16* __restrict__ Si,
    const float*  __restrict__ Ur, const float*  __restrict__ Ui,
    __bf16* __restrict__ Or, __bf16* __restrict__ Oi,
    float* __restrict__ Oabs)
{
    constexpr int PAD = 40;   // 32 data + 8 pad: breaks 8-way bank conflict
    __shared__ __bf16 lSr[64][PAD];
    __shared__ __bf16 lSi[HAS_IMAG ? 64 : 1][PAD];
    __shared__ __bf16 lUr[64][PAD];
    __shared__ __bf16 lUi[64][PAD];

    const int t    = threadIdx.x;
    const int lane = t & 63;
    const int wv   = t >> 6;
    const int wm   = wv >> 1;        // wave row (batch dim)
    const int wn   = wv & 1;         // wave col (output dim)
    const int fr   = lane & 15;      // fragment row/col
    const int kh   = (lane >> 4) * 8;// k-quarter offset

    const int b0 = blockIdx.y * 64;
    const int i0 = blockIdx.x * 64;

    // staging assignments
    const int srow = t >> 2, scol = (t & 3) * 8;  // state: 16B (8 bf16)/thread
    const int urow = t >> 3, ucol = (t & 7) * 4;  // U: 2x float4/thread

    const __bf16* gSr = Sr + (size_t)(b0 + srow) * DD + scol;
    const __bf16* gSi = HAS_IMAG ? (Si + (size_t)(b0 + srow) * DD + scol) : Sr;
    const float* gUr0 = Ur + (size_t)(i0 + urow) * DD + ucol;
    const float* gUr1 = Ur + (size_t)(i0 + urow + 32) * DD + ucol;
    const float* gUi0 = Ui + (size_t)(i0 + urow) * DD + ucol;
    const float* gUi1 = Ui + (size_t)(i0 + urow + 32) * DD + ucol;

    uint4 Asr, Asi; float4 Aur0, Aur1, Aui0, Aui1;   // prefetch set A
    uint4 Bsr, Bsi; float4 Bur0, Bur1, Bui0, Bui1;   // prefetch set B

    f32x4 acc_r[2][2] = {};
    f32x4 acc_i[2][2] = {};

#define LOADA(k0) do { Asr = *(const uint4*)(gSr + (k0)); \
    if constexpr (HAS_IMAG) Asi = *(const uint4*)(gSi + (k0)); \
    Aur0 = *(const float4*)(gUr0 + (k0)); Aur1 = *(const float4*)(gUr1 + (k0)); \
    Aui0 = *(const float4*)(gUi0 + (k0)); Aui1 = *(const float4*)(gUi1 + (k0)); } while (0)

#define LOADB(k0) do { Bsr = *(const uint4*)(gSr + (k0)); \
    if constexpr (HAS_IMAG) Bsi = *(const uint4*)(gSi + (k0)); \
    Bur0 = *(const float4*)(gUr0 + (k0)); Bur1 = *(const float4*)(gUr1 + (k0)); \
    Bui0 = *(const float4*)(gUi0 + (k0)); Bui1 = *(const float4*)(gUi1 + (k0)); } while (0)

#define CVT4(dst, f4) do { bf16x4 _w; \
    _w.x = (__bf16)(f4).x; _w.y = (__bf16)(f4).y; \
    _w.z = (__bf16)(f4).z; _w.w = (__bf16)(f4).w; \
    *(bf16x4*)(dst) = _w; } while (0)

#define WRITEA() do { *(uint4*)&lSr[srow][scol] = Asr; \
    if constexpr (HAS_IMAG) *(uint4*)&lSi[srow][scol] = Asi; \
    CVT4(&lUr[urow][ucol], Aur0); CVT4(&lUr[urow + 32][ucol], Aur1); \
    CVT4(&lUi[urow][ucol], Aui0); CVT4(&lUi[urow + 32][ucol], Aui1); } while (0)

#define WRITEB() do { *(uint4*)&lSr[srow][scol] = Bsr; \
    if constexpr (HAS_IMAG) *(uint4*)&lSi[srow][scol] = Bsi; \
    CVT4(&lUr[urow][ucol], Bur0); CVT4(&lUr[urow + 32][ucol], Bur1); \
    CVT4(&lUi[urow][ucol], Bui0); CVT4(&lUi[urow + 32][ucol], Bui1); } while (0)

    auto compute = [&]() {
        bf16x8 ar0 = *(const bf16x8*)&lSr[wm * 32 + fr][kh];
        bf16x8 ar1 = *(const bf16x8*)&lSr[wm * 32 + 16 + fr][kh];
        bf16x8 br0 = *(const bf16x8*)&lUr[wn * 32 + fr][kh];
        bf16x8 br1 = *(const bf16x8*)&lUr[wn * 32 + 16 + fr][kh];
        bf16x8 bi0 = *(const bf16x8*)&lUi[wn * 32 + fr][kh];
        bf16x8 bi1 = *(const bf16x8*)&lUi[wn * 32 + 16 + fr][kh];
        acc_r[0][0] = mfma16(ar0, br0, acc_r[0][0]);
        acc_r[0][1] = mfma16(ar0, br1, acc_r[0][1]);
        acc_r[1][0] = mfma16(ar1, br0, acc_r[1][0]);
        acc_r[1][1] = mfma16(ar1, br1, acc_r[1][1]);
        acc_i[0][0] = mfma16(ar0, bi0, acc_i[0][0]);
        acc_i[0][1] = mfma16(ar0, bi1, acc_i[0][1]);
        acc_i[1][0] = mfma16(ar1, bi0, acc_i[1][0]);
        acc_i[1][1] = mfma16(ar1, bi1, acc_i[1][1]);
        if constexpr (HAS_IMAG) {
            union { short8 s; bf16x8 b; } ai0, ai1, nai0, nai1;
            ai0.b = *(const bf16x8*)&lSi[wm * 32 + fr][kh];
            ai1.b = *(const bf16x8*)&lSi[wm * 32 + 16 + fr][kh];
            #pragma unroll
            for (int q = 0; q < 8; ++q) {
                nai0.s[q] = (short)(ai0.s[q] ^ (short)0x8000);
                nai1.s[q] = (short)(ai1.s[q] ^ (short)0x8000);
            }
            acc_r[0][0] = mfma16(nai0.b, bi0, acc_r[0][0]);
            acc_r[0][1] = mfma16(nai0.b, bi1, acc_r[0][1]);
            acc_r[1][0] = mfma16(nai1.b, bi0, acc_r[1][0]);
            acc_r[1][1] = mfma16(nai1.b, bi1, acc_r[1][1]);
            acc_i[0][0] = mfma16(ai0.b, br0, acc_i[0][0]);
            acc_i[0][1] = mfma16(ai0.b, br1, acc_i[0][1]);
            acc_i[1][0] = mfma16(ai1.b, br0, acc_i[1][0]);
            acc_i[1][1] = mfma16(ai1.b, br1, acc_i[1][1]);
        }
    };

    LOADA(0);
    for (int kk = 0; kk < 128; kk += 2) {
        WRITEA();
        LOADB((kk + 1) * 32);
        __syncthreads();
        compute();
        __syncthreads();
        WRITEB();
        if (kk + 2 < 128) LOADA((kk + 2) * 32);
        __syncthreads();
        compute();
        __syncthreads();
    }

    // epilogue: D layout col=lane&15 (N), row=(lane>>4)*4+reg (M)  [verified m89]
    const int orow = (lane >> 4) * 4;
    const int ocol = lane & 15;
    #pragma unroll
    for (int m = 0; m < 2; ++m)
        #pragma unroll
        for (int n = 0; n < 2; ++n) {
            int gi = i0 + wn * 32 + n * 16 + ocol;
            #pragma unroll
            for (int r = 0; r < 4; ++r) {
                int gb = b0 + wm * 32 + m * 16 + orow + r;
                float re = acc_r[m][n][r];
                float im = acc_i[m][n][r];
                size_t o = (size_t)gb * DD + gi;
                if constexpr (FINAL) {
                    Oabs[o] = sqrtf(re * re + im * im);
                } else {
                    Or[o] = (__bf16)re;
                    Oi[o] = (__bf16)im;
                }
            }
        }
#undef LOADA
#undef LOADB
#undef CVT4
#undef WRITEA
#undef WRITEB
}

// ------------------------------------------------------------- launch ----
extern "C" void kernel_launch(void* const* d_in, const int* in_sizes, int n_in,
                              void* d_out, int out_size, void* d_ws, size_t ws_size,
                              hipStream_t stream)
{
    const float* x   = (const float*)d_in[0];
    const float* u0r = (const float*)d_in[1];
    const float* u0i = (const float*)d_in[2];
    const float* u1r = (const float*)d_in[3];
    const float* u1i = (const float*)d_in[4];
    const float* u2r = (const float*)d_in[5];
    const float* u2i = (const float*)d_in[6];
    const float* u3r = (const float*)d_in[7];
    const float* u3i = (const float*)d_in[8];

    uint8_t* ws = (uint8_t*)d_ws;
    int*    permBuf = (int*)ws;                      // 16 KB
    __bf16* sAr = (__bf16*)(ws + 1u  * (1u << 20));  // 2 MB each
    __bf16* sAi = (__bf16*)(ws + 3u  * (1u << 20));
    __bf16* sBr = (__bf16*)(ws + 5u  * (1u << 20));
    __bf16* sBi = (__bf16*)(ws + 7u  * (1u << 20));

    perm_kernel<<<16, 256, 0, stream>>>(permBuf);
    normalize_kernel<<<256, 256, 0, stream>>>(x, sAr);

    dim3 grid(64, 4), blk(256);
    // stage 0: real input -> U0
    cgemm_kernel<false, false><<<grid, blk, 0, stream>>>(
        sAr, nullptr, u0r, u0i, sBr, sBi, nullptr);
    // perm
    gather_kernel<<<256, 256, 0, stream>>>(permBuf, sBr, sBi, sAr, sAi);
    // stage 1: U1
    cgemm_kernel<true, false><<<grid, blk, 0, stream>>>(
        sAr, sAi, u1r, u1i, sBr, sBi, nullptr);
    // stage 2: U2 (no perm between U1 and U2)
    cgemm_kernel<true, false><<<grid, blk, 0, stream>>>(
        sBr, sBi, u2r, u2i, sAr, sAi, nullptr);
    // perm
    gather_kernel<<<256, 256, 0, stream>>>(permBuf, sAr, sAi, sBr, sBi);
    // stage 3: U3 + |.| epilogue -> d_out (fp32)
    cgemm_kernel<true, true><<<grid, blk, 0, stream>>>(
        sBr, sBi, u3r, u3i, nullptr, nullptr, (float*)d_out);
}